// Round 9
// baseline (344.048 us; speedup 1.0000x reference)
//
#include <hip/hip_runtime.h>
#include <hip/hip_bf16.h>

#define HID 256
#define IND 21
#define ASTR2 72     // LDS row stride in bf16 elems for BK=64 tiles (+8 pad)
#define PB 6400      // edges per block in k_part / bhist
#define MAXB 512     // max buckets (N <= 131072)

typedef short short8 __attribute__((ext_vector_type(8)));
typedef float floatx4 __attribute__((ext_vector_type(4)));
typedef float floatx2 __attribute__((ext_vector_type(2)));

__device__ inline unsigned short f2bf(float f) {
  __hip_bfloat16 h = __float2bfloat16(f);  // RNE
  union { __hip_bfloat16 h; unsigned short u; } c;
  c.h = h;
  return c.u;
}

// pack float2 -> 2 bf16 by truncation (exact for values that came from fp8)
__device__ inline unsigned int pk_bf16_trunc(floatx2 p) {
  union { float f; unsigned int u; } a, b;
  a.f = p.x; b.f = p.y;
  return (b.u & 0xffff0000u) | (a.u >> 16);
}

// accumulate 8 fp8 bytes into 4 packed-f32 accumulators
__device__ inline void acc8p(uint2 v, floatx2* a) {
  a[0] += __builtin_amdgcn_cvt_pk_f32_fp8((int)v.x, false);
  a[1] += __builtin_amdgcn_cvt_pk_f32_fp8((int)v.x, true);
  a[2] += __builtin_amdgcn_cvt_pk_f32_fp8((int)v.y, false);
  a[3] += __builtin_amdgcn_cvt_pk_f32_fp8((int)v.y, true);
}

// decode uint4 of 16 fp8 -> 8 uints of 16 bf16 (exact)
__device__ inline void dec16(uint4 v, unsigned int* w) {
  unsigned int s4[4] = {v.x, v.y, v.z, v.w};
#pragma unroll
  for (int j = 0; j < 4; j++) {
    w[2 * j] = pk_bf16_trunc(__builtin_amdgcn_cvt_pk_f32_fp8((int)s4[j], false));
    w[2 * j + 1] = pk_bf16_trunc(__builtin_amdgcn_cvt_pk_f32_fp8((int)s4[j], true));
  }
}

// ---------------------------------------------------------------------------
// fused front kernel: [0,G1) linear_in | [G1,G1+256) wconv | rest bhist
// ---------------------------------------------------------------------------
__global__ __launch_bounds__(256) void k_front(
    const float* __restrict__ ns, const float* __restrict__ Win,
    const float* __restrict__ bin, unsigned int* __restrict__ xq,
    const float* __restrict__ Wself, const float* __restrict__ Wnei,
    unsigned short* __restrict__ WcT,
    const int* __restrict__ dst, int* __restrict__ bcnt,
    int N, int E, int nb2, int G1) {
  int blk = blockIdx.x;
  int tid = threadIdx.x;
  if (blk < G1) {
    __shared__ float s[8][IND];
    __shared__ float fx[8][257];
    int nb = blk * 8;
    if (tid < 8 * IND) {
      int idx = nb * IND + tid;
      s[tid / IND][tid % IND] = (idx < N * IND) ? ns[idx] : 0.f;
    }
    float w[IND];
#pragma unroll
    for (int k = 0; k < IND; k++) w[k] = Win[k * HID + tid];
    float b = bin[tid];
    __syncthreads();
#pragma unroll
    for (int j = 0; j < 8; j++) {
      float acc = b;
#pragma unroll
      for (int k = 0; k < IND; k++) acc += s[j][k] * w[k];
      fx[j][tid] = acc > 0.f ? acc : 0.f;
    }
    __syncthreads();
#pragma unroll
    for (int t = 0; t < 2; t++) {
      int wi = tid + t * 256;
      int j = wi >> 6, cw = wi & 63;
      int node = nb + j;
      if (node < N) {
        const float* fp = &fx[j][cw * 4];
        int lo = __builtin_amdgcn_cvt_pk_fp8_f32(fp[0], fp[1], 0, false);
        int full = __builtin_amdgcn_cvt_pk_fp8_f32(fp[2], fp[3], lo, true);
        xq[(size_t)node * 64 + cw] = (unsigned int)full;
      }
    }
  } else if (blk < G1 + 256) {
    int n = blk - G1;
#pragma unroll
    for (int t = 0; t < 2; t++) {
      int k = tid + t * 256;
      float v = (k < HID) ? Wself[k * HID + n] : Wnei[(k - HID) * HID + n];
      WcT[n * 512 + k] = f2bf(v);
    }
  } else {
    __shared__ int lh[MAXB];
    int e0 = (blk - G1 - 256) * PB;
    for (int b = tid; b < nb2; b += 256) lh[b] = 0;
    __syncthreads();
    int c = min(PB, E - e0);
    for (int i = tid; i < c; i += 256) atomicAdd(&lh[dst[e0 + i] >> 8], 1);
    __syncthreads();
    for (int b = tid; b < nb2; b += 256)
      if (lh[b]) atomicAdd(&bcnt[b], lh[b]);
  }
}

__global__ __launch_bounds__(512) void k_bscan(
    const int* __restrict__ bcnt, int* __restrict__ bbase, int* __restrict__ bcur,
    int* __restrict__ row_start, int E, int N, int nb2) {
  __shared__ int ts[512];
  int tid = threadIdx.x;
  int v = (tid < nb2) ? bcnt[tid] : 0;
  ts[tid] = v;
  __syncthreads();
  for (int off = 1; off < 512; off <<= 1) {
    int t = (tid >= off) ? ts[tid - off] : 0;
    __syncthreads();
    ts[tid] += t;
    __syncthreads();
  }
  if (tid < nb2) { bbase[tid] = ts[tid] - v; bcur[tid] = ts[tid] - v; }
  if (tid == 0) { bbase[nb2] = E; row_start[N] = E; }
}

// partition edges into per-bucket regions of ebuf (bucket = dst>>8).
// ebuf entry packed: (src << 8) | (dst & 255) -- 4 B/edge.
__global__ __launch_bounds__(256) void k_part(
    const int* __restrict__ src, const int* __restrict__ dst,
    int* __restrict__ bcur, unsigned int* __restrict__ ebuf, int E, int nb2) {
  __shared__ int lh[MAXB];
  int tid = threadIdx.x;
  int e0 = blockIdx.x * PB;
  for (int b = tid; b < nb2; b += 256) lh[b] = 0;
  __syncthreads();
  int cnt = min(PB, E - e0);
  for (int i = tid; i < cnt; i += 256) atomicAdd(&lh[dst[e0 + i] >> 8], 1);
  __syncthreads();
  for (int b = tid; b < nb2; b += 256) {
    int c = lh[b];
    lh[b] = (c > 0) ? atomicAdd(&bcur[b], c) : 0;
  }
  __syncthreads();
  for (int i = tid; i < cnt; i += 256) {
    int s = src[e0 + i];
    int d = dst[e0 + i];
    int pos = atomicAdd(&lh[d >> 8], 1);
    ebuf[pos] = ((unsigned)s << 8) | ((unsigned)d & 255u);
  }
}

// one block per bucket: LDS count + scan -> row_start; LDS cursors -> csr.
__global__ __launch_bounds__(256) void k_fill2(
    const unsigned int* __restrict__ ebuf, const int* __restrict__ bbase,
    int* __restrict__ row_start, int* __restrict__ csr, int N) {
  __shared__ int lcnt[256];
  __shared__ int lcur[256];
  __shared__ int ts[256];
  int b = blockIdx.x;
  int tid = threadIdx.x;
  int start = bbase[b], end = bbase[b + 1];
  lcnt[tid] = 0;
  __syncthreads();
  for (int i = start + tid; i < end; i += 256)
    atomicAdd(&lcnt[ebuf[i] & 255u], 1);
  __syncthreads();
  int v = lcnt[tid];
  ts[tid] = v;
  __syncthreads();
  for (int off = 1; off < 256; off <<= 1) {
    int t = (tid >= off) ? ts[tid - off] : 0;
    __syncthreads();
    ts[tid] += t;
    __syncthreads();
  }
  int excl = start + ts[tid] - v;
  int node = (b << 8) + tid;
  if (node < N) row_start[node] = excl;
  lcur[tid] = excl;
  __syncthreads();
  for (int i = start + tid; i < end; i += 256) {
    unsigned int e = ebuf[i];
    int pos = atomicAdd(&lcur[e & 255u], 1);
    csr[pos] = (int)(e >> 8);
  }
}

// ---------------------------------------------------------------------------
// k_agg: one wave per node; fp8 gather, 8 edges/iter, packed-f32 adds.
// ---------------------------------------------------------------------------
__global__ __launch_bounds__(256) void k_agg(
    const uint2* __restrict__ xq, const int* __restrict__ csr,
    const int* __restrict__ row_start, uint2* __restrict__ aggq, int N) {
  int wid = (int)((blockIdx.x * (unsigned)blockDim.x + threadIdx.x) >> 6);
  int lane = threadIdx.x & 63;
  int half = lane >> 5;
  int l32 = lane & 31;
  if (wid >= N) return;
  int start = row_start[wid];
  int end = row_start[wid + 1];
  int c = end - start;
  floatx2 a[4], b[4], d[4], e[4];
#pragma unroll
  for (int j = 0; j < 4; j++) {
    a[j] = (floatx2){0.f, 0.f}; b[j] = (floatx2){0.f, 0.f};
    d[j] = (floatx2){0.f, 0.f}; e[j] = (floatx2){0.f, 0.f};
  }
  int i = 0;
  for (; i + 8 <= c; i += 8) {
    int s0 = csr[start + i + half];
    int s1 = csr[start + i + 2 + half];
    int s2 = csr[start + i + 4 + half];
    int s3 = csr[start + i + 6 + half];
    uint2 v0 = xq[(size_t)s0 * 32 + l32];
    uint2 v1 = xq[(size_t)s1 * 32 + l32];
    uint2 v2 = xq[(size_t)s2 * 32 + l32];
    uint2 v3 = xq[(size_t)s3 * 32 + l32];
    acc8p(v0, a); acc8p(v1, b); acc8p(v2, d); acc8p(v3, e);
  }
  for (; i + 2 <= c; i += 2) {
    int s0 = csr[start + i + half];
    uint2 v0 = xq[(size_t)s0 * 32 + l32];
    acc8p(v0, a);
  }
  if ((c & 1) && half == 0) {
    int s0 = csr[start + c - 1];
    uint2 v0 = xq[(size_t)s0 * 32 + l32];
    acc8p(v0, a);
  }
#pragma unroll
  for (int j = 0; j < 4; j++) a[j] += b[j] + d[j] + e[j];

  float f[8];
#pragma unroll
  for (int j = 0; j < 4; j++) { f[2 * j] = a[j].x; f[2 * j + 1] = a[j].y; }
#pragma unroll
  for (int j = 0; j < 8; j++) f[j] += __shfl_xor(f[j], 32);

  if (half == 0) {
    float inv = 1.0f / fmaxf((float)c, 1.0f);
#pragma unroll
    for (int j = 0; j < 8; j++) f[j] *= inv;
    int lo0 = __builtin_amdgcn_cvt_pk_fp8_f32(f[0], f[1], 0, false);
    int w0  = __builtin_amdgcn_cvt_pk_fp8_f32(f[2], f[3], lo0, true);
    int lo1 = __builtin_amdgcn_cvt_pk_fp8_f32(f[4], f[5], 0, false);
    int w1  = __builtin_amdgcn_cvt_pk_fp8_f32(f[6], f[7], lo1, true);
    aggq[(size_t)wid * 32 + l32] = make_uint2((unsigned)w0, (unsigned)w1);
  }
}

// ---------------------------------------------------------------------------
// k_h: gsum[c] += sum_rows relu( [x|agg] @ WcT^T + b )
// 128 rows x 256 cols per block; BK=64 (8 K-iterations); software-pipelined:
// next tile's A/B global loads land in VGPRs during the MFMA phase (a barrier
// only drains lgkmcnt for reg-destined loads). A decoded fp8->bf16 at staging.
// ---------------------------------------------------------------------------
__global__ __launch_bounds__(256, 2) void k_h(
    const unsigned char* __restrict__ xq8, const unsigned char* __restrict__ aggq8,
    const unsigned short* __restrict__ WcT, const float* __restrict__ bself,
    const float* __restrict__ bnei, float* __restrict__ gsum, int N) {
  __shared__ __align__(16) unsigned short As[128 * ASTR2];  // 18 KB
  __shared__ __align__(16) unsigned short Bs[256 * ASTR2];  // 36 KB
  __shared__ float colsum[256];
  int tid = threadIdx.x;
  int rowBase = blockIdx.x * 128;
  int lane = tid & 63;
  int wid = tid >> 6;
  int wr = wid >> 1, wc = wid & 1;
  int n16 = lane & 15, quad = lane >> 4;

  colsum[tid] = 0.f;

  floatx4 acc[4][8];
#pragma unroll
  for (int i = 0; i < 4; i++)
#pragma unroll
    for (int j = 0; j < 8; j++) acc[i][j] = (floatx4){0.f, 0.f, 0.f, 0.f};

  // A staging coords: thread covers 32 fp8 (=2 uint4 src) of one row
  int ar = tid >> 1;          // 0..127
  int ah = tid & 1;           // 32-byte half of the 64-k chunk
  int gr = rowBase + ar;
  if (gr >= N) gr = N - 1;
  size_t abyte = (size_t)gr * HID + ah * 32;

  // B staging coords: 8 x (row br[j], seg bs[j]) - 256 rows x 8 segs of 8 shorts
  // idx = tid + j*256: br = idx>>3, bs = idx&7
  uint4 pa0, pa1, pb[8];
  {
    const unsigned char* ab = xq8;
    pa0 = *(const uint4*)(ab + abyte);
    pa1 = *(const uint4*)(ab + abyte + 16);
#pragma unroll
    for (int j = 0; j < 8; j++) {
      int idx = tid + j * 256;
      pb[j] = *(const uint4*)(WcT + (size_t)(idx >> 3) * 512 + (idx & 7) * 8);
    }
  }

  for (int it = 0; it < 8; it++) {
    int k0 = it * 64;
    // ---- write staged regs to LDS ----
    {
      unsigned int w[8];
      dec16(pa0, w);
      *(uint4*)(&As[ar * ASTR2 + ah * 32]) = make_uint4(w[0], w[1], w[2], w[3]);
      *(uint4*)(&As[ar * ASTR2 + ah * 32 + 8]) = make_uint4(w[4], w[5], w[6], w[7]);
      dec16(pa1, w);
      *(uint4*)(&As[ar * ASTR2 + ah * 32 + 16]) = make_uint4(w[0], w[1], w[2], w[3]);
      *(uint4*)(&As[ar * ASTR2 + ah * 32 + 24]) = make_uint4(w[4], w[5], w[6], w[7]);
#pragma unroll
      for (int j = 0; j < 8; j++) {
        int idx = tid + j * 256;
        *(uint4*)(&Bs[(idx >> 3) * ASTR2 + (idx & 7) * 8]) = pb[j];
      }
    }
    __syncthreads();
    // ---- prefetch next tile into regs (overlaps MFMA below) ----
    if (it < 7) {
      int kn = k0 + 64;
      const unsigned char* ab = (kn < HID) ? xq8 : aggq8;
      size_t off = abyte + (kn & 255);
      pa0 = *(const uint4*)(ab + off);
      pa1 = *(const uint4*)(ab + off + 16);
#pragma unroll
      for (int j = 0; j < 8; j++) {
        int idx = tid + j * 256;
        pb[j] = *(const uint4*)(WcT + (size_t)(idx >> 3) * 512 + kn + (idx & 7) * 8);
      }
    }
    // ---- MFMA phase: two 32-k sub-chunks ----
#pragma unroll
    for (int kk = 0; kk < 64; kk += 32) {
      short8 af[4];
#pragma unroll
      for (int rt = 0; rt < 4; rt++)
        af[rt] = *(const short8*)&As[(wr * 64 + rt * 16 + n16) * ASTR2 + kk + quad * 8];
#pragma unroll
      for (int ct = 0; ct < 8; ct++) {
        short8 bf = *(const short8*)&Bs[(wc * 128 + ct * 16 + n16) * ASTR2 + kk + quad * 8];
#pragma unroll
        for (int rt = 0; rt < 4; rt++)
          acc[rt][ct] = __builtin_amdgcn_mfma_f32_16x16x32_bf16(
              af[rt], bf, acc[rt][ct], 0, 0, 0);
      }
    }
    __syncthreads();
  }

  // epilogue: bias + relu + row-masked column sums (C/D: col=lane&15, row=quad*4+reg)
#pragma unroll
  for (int ct = 0; ct < 8; ct++) {
    int gcol = wc * 128 + ct * 16 + n16;
    float bb = bself[gcol] + bnei[gcol];
    float psum = 0.f;
#pragma unroll
    for (int rt = 0; rt < 4; rt++) {
#pragma unroll
      for (int r = 0; r < 4; r++) {
        int row = rowBase + wr * 64 + rt * 16 + quad * 4 + r;
        float v = acc[rt][ct][r] + bb;
        v = v > 0.f ? v : 0.f;
        if (row < N) psum += v;
      }
    }
    atomicAdd(&colsum[gcol], psum);
  }
  __syncthreads();
  atomicAdd(&gsum[tid], colsum[tid]);
}

// ---------------------------------------------------------------------------
// k_out: out = (gsum / N) @ W_out + b_out   single block, 256 threads
// ---------------------------------------------------------------------------
__global__ __launch_bounds__(HID) void k_out(
    const float* __restrict__ gsum, const float* __restrict__ Wout,
    const float* __restrict__ bout, float* __restrict__ out, float invN) {
  __shared__ float g[HID];
  int c = threadIdx.x;
  g[c] = gsum[c] * invN;
  __syncthreads();
  float acc = bout[c];
#pragma unroll 8
  for (int k = 0; k < HID; k++) acc += g[k] * Wout[k * HID + c];
  out[c] = acc;
}

extern "C" void kernel_launch(void* const* d_in, const int* in_sizes, int n_in,
                              void* d_out, int out_size, void* d_ws, size_t ws_size,
                              hipStream_t stream) {
  const float* ns    = (const float*)d_in[0];
  const float* Win   = (const float*)d_in[1];
  const float* bin   = (const float*)d_in[2];
  const float* Wself = (const float*)d_in[3];
  const float* bself = (const float*)d_in[4];
  const float* Wnei  = (const float*)d_in[5];
  const float* bnei  = (const float*)d_in[6];
  const float* Wout  = (const float*)d_in[7];
  const float* bout  = (const float*)d_in[8];
  const int*   eidx  = (const int*)d_in[9];

  int N = in_sizes[0] / IND;
  int E = in_sizes[9] / 2;
  const int* src = eidx;
  const int* dst = eidx + E;
  int nb2 = (N + 255) >> 8;

  // ws layout: xq[N*64] uint | aggq[N*64] uint | WcT[256*512] bf16 | csr[E] i |
  //   ebuf[E] uint | row_start[N+1] i | bcnt | bbase | bcur | gsum
  unsigned int* xq    = (unsigned int*)d_ws;
  unsigned int* aggq  = xq + (size_t)N * 64;
  unsigned short* WcT = (unsigned short*)(aggq + (size_t)N * 64);
  int* csr       = (int*)(WcT + 256 * 512);
  unsigned int* ebuf = (unsigned int*)(csr + E);
  int* row_start = (int*)(ebuf + E);
  int* bcnt      = row_start + N + 1;
  int* bbase     = bcnt + MAXB;
  int* bcur      = bbase + MAXB + 1;
  float* gsum    = (float*)(bcur + MAXB);

  hipMemsetAsync(bcnt, 0, MAXB * sizeof(int), stream);
  hipMemsetAsync(gsum, 0, HID * sizeof(float), stream);

  int G1 = (N + 7) / 8;
  int pgrid = (E + PB - 1) / PB;
  k_front<<<G1 + 256 + pgrid, 256, 0, stream>>>(
      ns, Win, bin, xq, Wself, Wnei, WcT, dst, bcnt, N, E, nb2, G1);

  k_bscan<<<1, 512, 0, stream>>>(bcnt, bbase, bcur, row_start, E, N, nb2);
  k_part<<<pgrid, 256, 0, stream>>>(src, dst, bcur, ebuf, E, nb2);
  k_fill2<<<nb2, 256, 0, stream>>>(ebuf, bbase, row_start, csr, N);

  int agrid = (N + 3) / 4;
  k_agg<<<agrid, 256, 0, stream>>>((const uint2*)xq, csr, row_start,
                                   (uint2*)aggq, N);

  int hgrid = (N + 127) / 128;
  k_h<<<hgrid, 256, 0, stream>>>((const unsigned char*)xq,
                                 (const unsigned char*)aggq,
                                 WcT, bself, bnei, gsum, N);

  k_out<<<1, HID, 0, stream>>>(gsum, Wout, bout, (float*)d_out, 1.0f / (float)N);
}